// Round 4
// baseline (2035.157 us; speedup 1.0000x reference)
//
#include <hip/hip_runtime.h>
#include <math.h>

#define BB 4
#define TT 2048
#define DD 1024
#define HH 128
#define EPSF 1e-6f
#define BT (BB*TT)   // 8192

typedef float f32x2 __attribute__((ext_vector_type(2)));

// ---------------------------------------------------------------------------
// Projection: P[bt][h] = sum_d x[bt][d] * W[h][d] + bias[h]
// ---------------------------------------------------------------------------
__global__ __launch_bounds__(256) void proj_kernel(
    const float* __restrict__ x,
    const float* __restrict__ Wq, const float* __restrict__ bq,
    const float* __restrict__ Wk, const float* __restrict__ bk,
    const float* __restrict__ Wv, const float* __restrict__ bv,
    float* __restrict__ Q, float* __restrict__ K, float* __restrict__ V)
{
    const int which = blockIdx.y;
    const float* W    = (which == 0) ? Wq : (which == 1) ? Wk : Wv;
    const float* bias = (which == 0) ? bq : (which == 1) ? bk : bv;
    float* P          = (which == 0) ? Q  : (which == 1) ? K  : V;

    const int row0 = blockIdx.x * 64;

    __shared__ float xT[32][68];
    __shared__ float wT[32][132];

    const int tid = threadIdx.x;
    const int tx = tid & 15;
    const int ty = tid >> 4;

    float acc[4][8];
    #pragma unroll
    for (int i = 0; i < 4; i++)
        #pragma unroll
        for (int j = 0; j < 8; j++) acc[i][j] = 0.f;

    for (int k0 = 0; k0 < DD; k0 += 32) {
        #pragma unroll
        for (int l = 0; l < 2; l++) {
            int f = tid + l * 256;
            int r = f >> 3;
            int cg = f & 7;
            float4 v = *(const float4*)(x + (size_t)(row0 + r) * DD + k0 + cg * 4);
            xT[cg*4+0][r] = v.x; xT[cg*4+1][r] = v.y;
            xT[cg*4+2][r] = v.z; xT[cg*4+3][r] = v.w;
        }
        #pragma unroll
        for (int l = 0; l < 4; l++) {
            int f = tid + l * 256;
            int h = f >> 3;
            int cg = f & 7;
            float4 v = *(const float4*)(W + (size_t)h * DD + k0 + cg * 4);
            wT[cg*4+0][h] = v.x; wT[cg*4+1][h] = v.y;
            wT[cg*4+2][h] = v.z; wT[cg*4+3][h] = v.w;
        }
        __syncthreads();
        #pragma unroll
        for (int kk = 0; kk < 32; kk++) {
            float4 xv = *(const float4*)&xT[kk][ty * 4];
            float4 w0 = *(const float4*)&wT[kk][tx * 8];
            float4 w1 = *(const float4*)&wT[kk][tx * 8 + 4];
            float xa[4] = {xv.x, xv.y, xv.z, xv.w};
            float wa[8] = {w0.x, w0.y, w0.z, w0.w, w1.x, w1.y, w1.z, w1.w};
            #pragma unroll
            for (int i = 0; i < 4; i++)
                #pragma unroll
                for (int j = 0; j < 8; j++)
                    acc[i][j] += xa[i] * wa[j];
        }
        __syncthreads();
    }

    #pragma unroll
    for (int i = 0; i < 4; i++) {
        int row = row0 + ty * 4 + i;
        #pragma unroll
        for (int j = 0; j < 8; j++) acc[i][j] += bias[tx * 8 + j];
        float4 o0 = {acc[i][0], acc[i][1], acc[i][2], acc[i][3]};
        float4 o1 = {acc[i][4], acc[i][5], acc[i][6], acc[i][7]};
        *(float4*)(P + (size_t)row * HH + tx * 8)     = o0;
        *(float4*)(P + (size_t)row * HH + tx * 8 + 4) = o1;
    }
}

// ---------------------------------------------------------------------------
// Precompute per-step scalars: rns[row] = (1/(||k||+eps), k.q).
// ---------------------------------------------------------------------------
__global__ __launch_bounds__(256) void rns_kernel(
    const float* __restrict__ K, const float* __restrict__ Q,
    float2* __restrict__ rns)
{
    const int row  = blockIdx.x * 4 + (threadIdx.x >> 6);
    const int lane = threadIdx.x & 63;
    const float* kp = K + (size_t)row * HH;
    const float* qp = Q + (size_t)row * HH;
    float k0 = kp[lane], k1 = kp[lane + 64];
    float q0 = qp[lane], q1 = qp[lane + 64];
    float p2  = k0 * k0 + k1 * k1;
    float pkq = k0 * q0 + k1 * q1;
    #pragma unroll
    for (int off = 32; off; off >>= 1) {
        p2  += __shfl_xor(p2, off);
        pkq += __shfl_xor(pkq, off);
    }
    if (lane == 0) {
        float rn = 1.0f / (sqrtf(p2) + EPSF);
        rns[row] = make_float2(rn, pkq);
    }
}

// quad butterfly sum via DPP (VALU, no DS pipe)
__device__ __forceinline__ float quad_red(float x) {
    x += __int_as_float(__builtin_amdgcn_mov_dpp(__float_as_int(x), 0xB1, 0xF, 0xF, true)); // [1,0,3,2]
    x += __int_as_float(__builtin_amdgcn_mov_dpp(__float_as_int(x), 0x4E, 0xF, 0xF, true)); // [2,3,0,1]
    return x;
}
// 8-lane butterfly sum: quad + xor-4 via ds_swizzle (BitMode 0x101F)
__device__ __forceinline__ float red8(float x) {
    x = quad_red(x);
    x += __int_as_float(__builtin_amdgcn_ds_swizzle(__float_as_int(x), 0x101F));
    return x;
}

// ---------------------------------------------------------------------------
// Sequential scan v5: 1024 threads (16 waves, 4/SIMD) for latency hiding.
// Thread owns A[r][c0..c0+15], M[r][c0..c0+15]; r = tid>>3, c0 = (tid&7)*16.
// Same one-barrier structure as v4; per-thread VALU and LDS reads halved;
// row-group reductions are 8-lane (quad DPP + one ds_swizzle xor-4).
// Padded LDS layout: col c at float offset (c>>4)*20 + (c&15); the 8 group
// starts hit banks {0,20,8,28,16,4,24,12} so the 8 o8-groups' float4 reads
// cover all 32 banks exactly (conflict-free, 8-way lane dedup).
// VGPR budget sized for the mandatory 4 waves/SIMD (<=128).
// ---------------------------------------------------------------------------
__global__ __launch_bounds__(1024, 1) void scan_kernel(
    const float* __restrict__ Q, const float* __restrict__ K,
    const float* __restrict__ V, const float2* __restrict__ rns,
    float* __restrict__ O)
{
    const int b   = blockIdx.x;
    const int tid = threadIdx.x;
    const int r   = tid >> 3;     // row 0..127
    const int o8  = tid & 7;      // column octant
    const int c0  = o8 * 16;

    __shared__ float Aus[2][8 * 20];        // (A k) broadcast, padded
    __shared__ float kqs[2][2][8 * 20];     // [buf][0=k,1=q], padded
    __shared__ float vbuf[2][128];          // v, linear

    f32x2 A2[8], M2[8];
    #pragma unroll
    for (int j = 0; j < 8; j++) {
        M2[j] = (f32x2){0.f, 0.f};
        A2[j].x = (c0 + 2 * j     == r) ? 1.0f : 0.0f;
        A2[j].y = (c0 + 2 * j + 1 == r) ? 1.0f : 0.0f;
    }

    const float* Qb = Q + (size_t)b * TT * HH;
    const float* Kb = K + (size_t)b * TT * HH;
    const float* Vb = V + (size_t)b * TT * HH;
    float*       Ob = O + (size_t)b * TT * HH;
    const float2* rns_b = rns + (size_t)b * TT;

    const int woff = (r >> 4) * 20 + (r & 15);   // my row's slot in Aus
    const int roff = o8 * 20;                    // my read base (padded)

    // loader role: 96 threads, one float4 each per step
    const bool ldr   = tid < 96;
    const int  which = tid >> 5;                 // 0=k 1=q 2=v
    const int  l32   = tid & 31;
    const float* src = (which == 0) ? Kb : (which == 1) ? Qb : Vb;
    const int  lpoff = (l32 >> 2) * 20 + (l32 & 3) * 4;  // padded f4 offset

    float4 pld = {0.f, 0.f, 0.f, 0.f};

    // prologue: stage t=0, prefetch t=1
    if (ldr) {
        float4 d0 = *(const float4*)(src + l32 * 4);
        if (which < 2) *(float4*)&kqs[0][which][lpoff] = d0;
        else           *(float4*)&vbuf[0][l32 * 4]     = d0;
        pld = *(const float4*)(src + (size_t)HH + l32 * 4);
    }
    float2 rs_cur = rns_b[0];
    float2 rs_nxt = rns_b[1];
    __syncthreads();

    f32x2 kk2[8], qq2[8];
    #pragma unroll
    for (int j = 0; j < 4; j++) {
        float4 tk = *(const float4*)&kqs[0][0][roff + 4 * j];
        float4 tq = *(const float4*)&kqs[0][1][roff + 4 * j];
        kk2[2*j]   = (f32x2){tk.x, tk.y}; kk2[2*j+1] = (f32x2){tk.z, tk.w};
        qq2[2*j]   = (f32x2){tq.x, tq.y}; qq2[2*j+1] = (f32x2){tq.z, tq.w};
    }
    float vr = vbuf[0][r];

    for (int t = 0; t < TT; t++) {
        const int buf  = t & 1;
        const int nbuf = buf ^ 1;

        // --- praw = (A k)[r] partial over my 16 cols (packed)
        f32x2 pa0 = {0.f, 0.f}, pa1 = {0.f, 0.f};
        #pragma unroll
        for (int j = 0; j < 8; j += 2) {
            pa0 += A2[j]     * kk2[j];
            pa1 += A2[j + 1] * kk2[j + 1];
        }
        f32x2 pav = pa0 + pa1;
        float praw = red8(pav.x + pav.y);
        if (o8 == 0) Aus[buf][woff] = praw;

        // stage t+1 into LDS; issue global load for t+2
        if (ldr && t + 1 < TT) {
            if (which < 2) *(float4*)&kqs[nbuf][which][lpoff] = pld;
            else           *(float4*)&vbuf[nbuf][l32 * 4]     = pld;
            if (t + 2 < TT)
                pld = *(const float4*)(src + (size_t)(t + 2) * HH + l32 * 4);
        }

        __syncthreads();   // the ONE barrier: Aus[buf] + kqs/vbuf[nbuf] ready

        // --- read z~raw at my columns (conflict-free padded layout)
        f32x2 av2[8];
        #pragma unroll
        for (int j = 0; j < 4; j++) {
            float4 tv = *(const float4*)&Aus[buf][roff + 4 * j];
            av2[2*j]   = (f32x2){tv.x, tv.y};
            av2[2*j+1] = (f32x2){tv.z, tv.w};
        }

        // --- three independent packed dots: pd = k.av, pq = q.av, x = M.q
        f32x2 pdv = {0.f, 0.f}, pqv = {0.f, 0.f}, xv = {0.f, 0.f};
        #pragma unroll
        for (int j = 0; j < 8; j++) {
            f32x2 a = av2[j];
            pdv += a * kk2[j];
            pqv += a * qq2[j];
            xv  += M2[j] * qq2[j];
        }
        float pd = red8(pdv.x + pdv.y);
        float pq = red8(pqv.x + pqv.y);
        float x  = red8(xv.x + xv.y);

        const float rn  = rs_cur.x;
        const float s   = rs_cur.y;
        const float rn2 = rn * rn;
        const float inv_d = __builtin_amdgcn_rcpf(1.0f + rn2 * pd);
        const float cA = praw * rn2 * inv_d;      // A -= cA * praw_c
        const float cM = vr * s * rn * inv_d;     // M += cM * praw_c
        const float o  = x + cM * pq;             // (M_new q)[r]
        if (o8 == 0) Ob[(size_t)t * HH + r] = o;

        // --- rank-1 updates (only these trail inv_d)
        const f32x2 cAv = {cA, cA};
        const f32x2 cMv = {cM, cM};
        #pragma unroll
        for (int j = 0; j < 8; j++) {
            f32x2 a = av2[j];
            A2[j] -= cAv * a;
            M2[j] += cMv * a;
        }

        // --- refills for t+1 (dead registers; ordered by this step's barrier
        //     against writes, and by barrier t+1 against t+2 overwrites)
        #pragma unroll
        for (int j = 0; j < 4; j++) {
            float4 tk = *(const float4*)&kqs[nbuf][0][roff + 4 * j];
            float4 tq = *(const float4*)&kqs[nbuf][1][roff + 4 * j];
            kk2[2*j]   = (f32x2){tk.x, tk.y}; kk2[2*j+1] = (f32x2){tk.z, tk.w};
            qq2[2*j]   = (f32x2){tq.x, tq.y}; qq2[2*j+1] = (f32x2){tq.z, tq.w};
        }
        vr = vbuf[nbuf][r];
        rs_cur = rs_nxt;
        if (t + 2 < TT) rs_nxt = rns_b[t + 2];
    }
}

// ---------------------------------------------------------------------------
// Output: out[bt][d] = sum_h O[bt][h] * Wo[d][h] + bo[d]
// ---------------------------------------------------------------------------
__global__ __launch_bounds__(256) void out_kernel(
    const float* __restrict__ O, const float* __restrict__ Wo,
    const float* __restrict__ bo, float* __restrict__ out)
{
    const int row0 = blockIdx.x * 64;
    const int d0   = blockIdx.y * 128;

    __shared__ float oT[32][68];
    __shared__ float woT[32][132];

    const int tid = threadIdx.x;
    const int tx = tid & 15;
    const int ty = tid >> 4;

    float acc[4][8];
    #pragma unroll
    for (int i = 0; i < 4; i++)
        #pragma unroll
        for (int j = 0; j < 8; j++) acc[i][j] = 0.f;

    for (int k0 = 0; k0 < HH; k0 += 32) {
        #pragma unroll
        for (int l = 0; l < 2; l++) {
            int f = tid + l * 256;
            int r = f >> 3;
            int cg = f & 7;
            float4 v = *(const float4*)(O + (size_t)(row0 + r) * HH + k0 + cg * 4);
            oT[cg*4+0][r] = v.x; oT[cg*4+1][r] = v.y;
            oT[cg*4+2][r] = v.z; oT[cg*4+3][r] = v.w;
        }
        #pragma unroll
        for (int l = 0; l < 4; l++) {
            int f = tid + l * 256;
            int d = f >> 3;
            int cg = f & 7;
            float4 v = *(const float4*)(Wo + (size_t)(d0 + d) * HH + k0 + cg * 4);
            woT[cg*4+0][d] = v.x; woT[cg*4+1][d] = v.y;
            woT[cg*4+2][d] = v.z; woT[cg*4+3][d] = v.w;
        }
        __syncthreads();
        #pragma unroll
        for (int kk = 0; kk < 32; kk++) {
            float4 ov = *(const float4*)&oT[kk][ty * 4];
            float4 w0 = *(const float4*)&woT[kk][tx * 8];
            float4 w1 = *(const float4*)&woT[kk][tx * 8 + 4];
            float oa[4] = {ov.x, ov.y, ov.z, ov.w};
            float wa[8] = {w0.x, w0.y, w0.z, w0.w, w1.x, w1.y, w1.z, w1.w};
            #pragma unroll
            for (int i = 0; i < 4; i++)
                #pragma unroll
                for (int j = 0; j < 8; j++)
                    acc[i][j] += oa[i] * wa[j];
        }
        __syncthreads();
    }

    #pragma unroll
    for (int i = 0; i < 4; i++) {
        int row = row0 + ty * 4 + i;
        #pragma unroll
        for (int j = 0; j < 8; j++) acc[i][j] += bo[d0 + tx * 8 + j];
        float4 o0 = {acc[i][0], acc[i][1], acc[i][2], acc[i][3]};
        float4 o1 = {acc[i][4], acc[i][5], acc[i][6], acc[i][7]};
        *(float4*)(out + (size_t)row * DD + d0 + tx * 8)     = o0;
        *(float4*)(out + (size_t)row * DD + d0 + tx * 8 + 4) = o1;
    }
}

extern "C" void kernel_launch(void* const* d_in, const int* in_sizes, int n_in,
                              void* d_out, int out_size, void* d_ws, size_t ws_size,
                              hipStream_t stream) {
    const float* x  = (const float*)d_in[0];
    const float* Wq = (const float*)d_in[1];
    const float* bq = (const float*)d_in[2];
    const float* Wk = (const float*)d_in[3];
    const float* bk = (const float*)d_in[4];
    const float* Wv = (const float*)d_in[5];
    const float* bv = (const float*)d_in[6];
    const float* Wo = (const float*)d_in[7];
    const float* bo = (const float*)d_in[8];
    float* out = (float*)d_out;

    float* ws = (float*)d_ws;
    float* Q = ws;
    float* K = ws + (size_t)BT * HH;
    float* V = ws + (size_t)2 * BT * HH;
    float* O = ws + (size_t)3 * BT * HH;
    // rns scalars live in d_out: it is scratch until out_kernel runs
    float2* rns = (float2*)d_out;

    dim3 pgrid(BT / 64, 3);
    proj_kernel<<<pgrid, 256, 0, stream>>>(x, Wq, bq, Wk, bk, Wv, bv, Q, K, V);

    rns_kernel<<<BT / 4, 256, 0, stream>>>(K, Q, rns);

    scan_kernel<<<BB, 1024, 0, stream>>>(Q, K, V, rns, O);

    dim3 ogrid(BT / 64, DD / 128);
    out_kernel<<<ogrid, 256, 0, stream>>>(O, Wo, bo, out);
}